// Round 13
// baseline (246.135 us; speedup 1.0000x reference)
//
#include <hip/hip_runtime.h>

// HalfEdgeMeshPool: segment-mean over groups.
// feat: [B, C, N] f32, gid: [B, N] i32 in [0,T), out: [B, C, T] f32.
//
// R1/R2: LDS f32 atomics serialize ~3.2 cyc/lane -> 428us floor.
// R3: random 4B global gather = 14.5x line over-fetch -> 1.7ms.
// R5/R6: sort+transpose (820MB, 2 passes) -> 250us.
// R7: fused single-pass, 160KB LDS -> 318us (1 block/CU, serialized phases).
// R8: fused, 80KB LDS, mt[t][8] member table -> 199us.
// R9/R10: PAD=4 + ext tables -> 315us REGRESSION (scattered-write amplification).
// R11: R8 + 1024-thr blocks (2048 thr/CU = HW max) -> 142us.
// R12: prepass trim + rcp -> 140us (prepass was already small; fused ~125us is
//      the consumer, ~2.4x its 52-78us HBM floor -> phase-2 gather issue).
// R13: slot-major mtS[k][b*T+t] + exec-masked k-loop with __all early-break:
//      gather work drops from uniform 8/group to ~mean cnt (2)/group; index
//      loads coalesced per k; stores stay t-ordered; no sentinel init needed.
static constexpr int B = 8;
static constexpr int C = 256;
static constexpr int N = 40000;
static constexpr int T = 20000;
static constexpr int PAD = 8;                  // mtS slots per group (P(cnt>8)~1e-3)
static constexpr int MAXH = N / (PAD + 1) + 8; // heavy-group cap per b
static constexpr int FTH = 1024;               // fused block threads
static constexpr int BT = B * T;

typedef float  f32x4 __attribute__((ext_vector_type(4)));
typedef ushort u16x4 __attribute__((ext_vector_type(4)));

__device__ __forceinline__ ushort f2bf(float v) {
    unsigned u = __float_as_uint(v);
    u += 0x7FFFu + ((u >> 16) & 1u);  // round-to-nearest-even
    return (ushort)(u >> 16);
}
__device__ __forceinline__ float bf2f(ushort u) {
    return __uint_as_float((unsigned)u << 16);
}

// ---- init: head=0, hcnt=ocnt=0 (mtS needs no sentinel: k-loop is cnt-masked) ----
__global__ void __launch_bounds__(256) hemp_init_kernel(int* __restrict__ head,
                                                        int* __restrict__ hcnt,
                                                        int* __restrict__ ocnt) {
    const int stride = gridDim.x * 256;
    int i = blockIdx.x * 256 + threadIdx.x;
    for (int k = i; k < BT; k += stride) head[k] = 0;
    if (i < B) { hcnt[i] = 0; ocnt[i] = 0; }
}

// ---- fill (int4): rank r -> mtS[r][b*T+g]; overflow -> list ----
__global__ void __launch_bounds__(256) hemp_fill_kernel(const int* __restrict__ gid,
                                                        int* __restrict__ head,
                                                        ushort* __restrict__ mtS,
                                                        unsigned* __restrict__ of,
                                                        int* __restrict__ hg,
                                                        int* __restrict__ hcnt,
                                                        int* __restrict__ ocnt) {
    int idx = blockIdx.x * 256 + threadIdx.x;
    if (idx >= B * N / 4) return;
    const int b = idx / (N / 4);
    const int i4 = idx - b * (N / 4);
    const int4 g = reinterpret_cast<const int4*>(gid + (size_t)b * N)[i4];
    int* hb = head + b * T;
    const int n = i4 * 4;
    #pragma unroll
    for (int k = 0; k < 4; ++k) {
        const int gg = (k == 0) ? g.x : (k == 1) ? g.y : (k == 2) ? g.z : g.w;
        const int r = atomicAdd(&hb[gg], 1);  // head ends as per-group count
        if (r < PAD) {
            mtS[(size_t)r * BT + b * T + gg] = (ushort)(n + k);
        } else {
            int o = atomicAdd(&ocnt[b], 1);
            of[(size_t)b * N + o] = ((unsigned)gg << 16) | (unsigned)(n + k);
            if (r == PAD) {  // first overflow: register gg as heavy
                int h = atomicAdd(&hcnt[b], 1);
                hg[b * MAXH + h] = gg;
            }
        }
    }
}

// ---- fused: one block per (b,c). Stream row->LDS bf16; masked k-loop gather ----
__global__ void __launch_bounds__(FTH) hemp_fused_kernel(const float* __restrict__ feat,
                                                         const ushort* __restrict__ mtS,
                                                         const int* __restrict__ head,
                                                         const unsigned* __restrict__ of,
                                                         const int* __restrict__ hg,
                                                         const int* __restrict__ hcnt,
                                                         const int* __restrict__ ocnt,
                                                         float* __restrict__ out) {
    __shared__ ushort row_bf[N];  // 80000 B -> 2 blocks/CU
    const int tid = threadIdx.x;
    const int b = blockIdx.x >> 8;  // same-b blocks adjacent -> mtS/cnt L2-hot
    const int c = blockIdx.x & 255;

    // Phase 1: stream feature row into LDS as bf16 (unroll-2 for load depth)
    const f32x4* __restrict__ f4 =
        reinterpret_cast<const f32x4*>(feat + (size_t)(b * C + c) * N);
    for (int i = tid; i < N / 4; i += 2 * FTH) {
        f32x4 v0 = f4[i];
        const int i2 = i + FTH;
        const bool ok = i2 < N / 4;
        f32x4 v1 = {};
        if (ok) v1 = f4[i2];
        u16x4 w0 = {f2bf(v0.x), f2bf(v0.y), f2bf(v0.z), f2bf(v0.w)};
        *reinterpret_cast<u16x4*>(&row_bf[i * 4]) = w0;
        if (ok) {
            u16x4 w1 = {f2bf(v1.x), f2bf(v1.y), f2bf(v1.z), f2bf(v1.w)};
            *reinterpret_cast<u16x4*>(&row_bf[i2 * 4]) = w1;
        }
    }
    __syncthreads();

    // Phase 2: per group, k-loop over slots with cnt-mask + wave early-break.
    // Index loads coalesced (u16 stride-1 in t per k-plane). Unroll-2 for ILP.
    const ushort* __restrict__ mtb = mtS + b * T;  // + k*BT per slot plane
    const int* __restrict__ cntb = head + b * T;
    float* __restrict__ orow = out + (size_t)(b * C + c) * T;
    for (int t = tid; t < T; t += 2 * FTH) {
        const int t1 = t + FTH;
        const bool ok = t1 < T;
        const int cn0 = cntb[t];
        const int cn1 = ok ? cntb[t1] : 0;
        const int k0 = min(cn0, PAD);
        const int k1 = min(cn1, PAD);
        float s0 = 0.0f, s1 = 0.0f;
        for (int k = 0; k < PAD; ++k) {
            if (__all(k >= k0 && k >= k1)) break;
            const ushort* plane = mtb + (size_t)k * BT;
            if (k < k0) s0 += bf2f(row_bf[plane[t]]);
            if (k < k1) s1 += bf2f(row_bf[plane[t1]]);
        }
        if (cn0 <= PAD)
            __builtin_nontemporal_store(
                s0 * __builtin_amdgcn_rcpf(fmaxf((float)cn0, 1.0f)), orow + t);
        if (ok && cn1 <= PAD)
            __builtin_nontemporal_store(
                s1 * __builtin_amdgcn_rcpf(fmaxf((float)cn1, 1.0f)), orow + t1);
    }

    // Epilogue: heavy groups (count>PAD, ~22 per mesh) — mtS + overflow scan
    const int H = hcnt[b];
    if (H > 0) {
        const int O = ocnt[b];
        const unsigned* __restrict__ ofb = of + (size_t)b * N;
        for (int i = tid; i < H; i += FTH) {
            const int g = hg[b * MAXH + i];
            float s = 0.0f;
            #pragma unroll
            for (int k = 0; k < PAD; ++k) s += bf2f(row_bf[mtb[(size_t)k * BT + g]]);
            for (int e = 0; e < O; ++e) {
                unsigned w = ofb[e];
                if ((w >> 16) == (unsigned)g) s += bf2f(row_bf[w & 0xFFFFu]);
            }
            orow[g] = s / (float)cntb[g];
        }
    }
}

// ---- fallback (ws too small): R2 LDS-atomic kernel ----
static constexpr int BLK = 1024;
__global__ void __launch_bounds__(256) hemp_zero_kernel(int* __restrict__ counts) {
    int i = blockIdx.x * 256 + threadIdx.x;
    if (i < BT) counts[i] = 0;
}
__global__ void __launch_bounds__(256) hemp_count1_kernel(const int* __restrict__ gid,
                                                          int* __restrict__ counts) {
    int idx = blockIdx.x * 256 + threadIdx.x;
    if (idx < B * N) {
        int b = idx / N;
        atomicAdd(&counts[b * T + gid[idx]], 1);
    }
}
__global__ void __launch_bounds__(BLK) hemp_atomic_kernel(const float* __restrict__ feat,
                                                          const int* __restrict__ gid,
                                                          const int* __restrict__ counts,
                                                          float* __restrict__ out) {
    extern __shared__ float lds_sum[];
    const int tid = threadIdx.x;
    const int b = blockIdx.x >> 8;
    const int c = blockIdx.x & 255;
    float4* ls4 = reinterpret_cast<float4*>(lds_sum);
    for (int t = tid; t < T / 4; t += BLK) ls4[t] = make_float4(0.f, 0.f, 0.f, 0.f);
    __syncthreads();
    const float4* f4 = reinterpret_cast<const float4*>(feat + (size_t)(b * C + c) * N);
    const int4* g4 = reinterpret_cast<const int4*>(gid + (size_t)b * N);
    for (int i = tid; i < N / 4; i += BLK) {
        float4 v = f4[i];
        int4 g = g4[i];
        unsafeAtomicAdd(&lds_sum[g.x], v.x);
        unsafeAtomicAdd(&lds_sum[g.y], v.y);
        unsafeAtomicAdd(&lds_sum[g.z], v.z);
        unsafeAtomicAdd(&lds_sum[g.w], v.w);
    }
    __syncthreads();
    const int4* cnt4 = reinterpret_cast<const int4*>(counts + (size_t)b * T);
    float4* out4 = reinterpret_cast<float4*>(out + (size_t)(b * C + c) * T);
    for (int t = tid; t < T / 4; t += BLK) {
        int4 cn = cnt4[t];
        float4 s = ls4[t];
        float4 r;
        r.x = s.x / fmaxf((float)cn.x, 1.0f);
        r.y = s.y / fmaxf((float)cn.y, 1.0f);
        r.z = s.z / fmaxf((float)cn.z, 1.0f);
        r.w = s.w / fmaxf((float)cn.w, 1.0f);
        out4[t] = r;
    }
}

extern "C" void kernel_launch(void* const* d_in, const int* in_sizes, int n_in,
                              void* d_out, int out_size, void* d_ws, size_t ws_size,
                              hipStream_t stream) {
    const float* feat = (const float*)d_in[0];
    const int* gid = (const int*)d_in[1];
    float* out = (float*)d_out;

    // ws: head[B*T] i32 | mtS[PAD][B*T] u16 | of[B*N] u32 | hg[B*MAXH] i32 | hcnt[B] | ocnt[B]
    char* p = (char*)d_ws;
    int* head = (int*)p;            p += (size_t)BT * 4;
    ushort* mtS = (ushort*)p;       p += (size_t)PAD * BT * 2;
    unsigned* of = (unsigned*)p;    p += (size_t)B * N * 4;
    int* hg = (int*)p;              p += (size_t)B * MAXH * 4;
    int* hcnt = (int*)p;            p += (size_t)B * 4;
    int* ocnt = (int*)p;            p += (size_t)B * 4;
    size_t need = (size_t)(p - (char*)d_ws);

    if (ws_size >= need) {
        hemp_init_kernel<<<640, 256, 0, stream>>>(head, hcnt, ocnt);
        hemp_fill_kernel<<<(B * N / 4 + 255) / 256, 256, 0, stream>>>(gid, head, mtS, of,
                                                                      hg, hcnt, ocnt);
        hemp_fused_kernel<<<B * C, FTH, 0, stream>>>(feat, mtS, head, of, hg,
                                                     hcnt, ocnt, out);
    } else {
        int* cnts = (int*)d_ws;
        hemp_zero_kernel<<<(BT + 255) / 256, 256, 0, stream>>>(cnts);
        hemp_count1_kernel<<<(B * N + 255) / 256, 256, 0, stream>>>(gid, cnts);
        const size_t lds_bytes = (size_t)T * sizeof(float);
        hipFuncSetAttribute(reinterpret_cast<const void*>(hemp_atomic_kernel),
                            hipFuncAttributeMaxDynamicSharedMemorySize, (int)lds_bytes);
        hemp_atomic_kernel<<<B * C, BLK, lds_bytes, stream>>>(feat, gid, cnts, out);
    }
}

// Round 14
// 145.607 us; speedup vs baseline: 1.6904x; 1.6904x over previous
//
#include <hip/hip_runtime.h>

// HalfEdgeMeshPool: segment-mean over groups.
// feat: [B, C, N] f32, gid: [B, N] i32 in [0,T), out: [B, C, T] f32.
//
// R1/R2: LDS f32 atomics serialize ~3.2 cyc/lane -> 428us floor.
// R3: random 4B global gather = 14.5x line over-fetch -> 1.7ms.
// R5/R6: sort+transpose (820MB, 2 passes) -> 250us.
// R7: fused single-pass, 160KB LDS -> 318us (1 block/CU, serialized phases).
// R8: fused, 80KB LDS, mt[t][8] member table -> 199us.
// R9/R10: PAD=4 + ext tables -> 315us REGRESSION (scattered-write amplification).
// R11: R8 + 1024-thr blocks (2048 thr/CU = HW max) -> 142us.
// R12: prepass trim + rcp -> 140us. R13: slot-major mtS k-loop -> 246us
//      REGRESSION (8x tiny dependent global index loads replaced one 16B load).
// R14: R12 exactly, + per-lane predication (k < cnt) on the 8 unrolled LDS
//      gathers (exec-masked lanes issue no LDS request: pipe work 8 -> ~2 per
//      group; mt load/stores unchanged), sentinel init dropped (never read),
//      phase-1 unroll-4 for deeper load queue. Clean A/B on the gather pipe.
static constexpr int B = 8;
static constexpr int C = 256;
static constexpr int N = 40000;
static constexpr int T = 20000;
static constexpr int PAD = 8;                  // mt slots per group (P(cnt>8)~1e-3)
static constexpr int MAXH = N / (PAD + 1) + 8; // heavy-group cap per b
static constexpr int FTH = 1024;               // fused block threads

typedef float  f32x4 __attribute__((ext_vector_type(4)));
typedef ushort u16x4 __attribute__((ext_vector_type(4)));
typedef ushort u16x8 __attribute__((ext_vector_type(8)));

__device__ __forceinline__ ushort f2bf(float v) {
    unsigned u = __float_as_uint(v);
    u += 0x7FFFu + ((u >> 16) & 1u);  // round-to-nearest-even
    return (ushort)(u >> 16);
}
__device__ __forceinline__ float bf2f(ushort u) {
    return __uint_as_float((unsigned)u << 16);
}

// ---- init: head=0, hcnt=ocnt=0 (no mt sentinel: gathers are cnt-predicated) ----
__global__ void __launch_bounds__(256) hemp_init_kernel(int* __restrict__ head,
                                                        int* __restrict__ hcnt,
                                                        int* __restrict__ ocnt) {
    const int stride = gridDim.x * 256;
    int i = blockIdx.x * 256 + threadIdx.x;
    for (int k = i; k < B * T; k += stride) head[k] = 0;
    if (i < B) { hcnt[i] = 0; ocnt[i] = 0; }
}

// ---- fill (int4): rank within group -> mt slot; overflow -> list ----
__global__ void __launch_bounds__(256) hemp_fill_kernel(const int* __restrict__ gid,
                                                        int* __restrict__ head,
                                                        ushort* __restrict__ mt,
                                                        unsigned* __restrict__ of,
                                                        int* __restrict__ hg,
                                                        int* __restrict__ hcnt,
                                                        int* __restrict__ ocnt) {
    int idx = blockIdx.x * 256 + threadIdx.x;
    if (idx >= B * N / 4) return;
    const int b = idx / (N / 4);
    const int i4 = idx - b * (N / 4);
    const int4 g = reinterpret_cast<const int4*>(gid + (size_t)b * N)[i4];
    int* hb = head + b * T;
    const int n = i4 * 4;
    #pragma unroll
    for (int k = 0; k < 4; ++k) {
        const int gg = (k == 0) ? g.x : (k == 1) ? g.y : (k == 2) ? g.z : g.w;
        const int r = atomicAdd(&hb[gg], 1);  // head ends as per-group count
        if (r < PAD) {
            mt[((size_t)(b * T + gg)) * PAD + r] = (ushort)(n + k);
        } else {
            int o = atomicAdd(&ocnt[b], 1);
            of[(size_t)b * N + o] = ((unsigned)gg << 16) | (unsigned)(n + k);
            if (r == PAD) {  // first overflow: register gg as heavy
                int h = atomicAdd(&hcnt[b], 1);
                hg[b * MAXH + h] = gg;
            }
        }
    }
}

// ---- fused: one block per (b,c). Stream row->LDS bf16; predicated gathers ----
__global__ void __launch_bounds__(FTH) hemp_fused_kernel(const float* __restrict__ feat,
                                                         const ushort* __restrict__ mt,
                                                         const int* __restrict__ head,
                                                         const unsigned* __restrict__ of,
                                                         const int* __restrict__ hg,
                                                         const int* __restrict__ hcnt,
                                                         const int* __restrict__ ocnt,
                                                         float* __restrict__ out) {
    __shared__ ushort row_bf[N];  // 80000 B -> 2 blocks/CU
    const int tid = threadIdx.x;
    const int b = blockIdx.x >> 8;  // same-b blocks adjacent -> mt/cnt L2-hot
    const int c = blockIdx.x & 255;

    // Phase 1: stream feature row into LDS as bf16 (unroll-4 load depth)
    const f32x4* __restrict__ f4 =
        reinterpret_cast<const f32x4*>(feat + (size_t)(b * C + c) * N);
    for (int i = tid; i < N / 4; i += 4 * FTH) {
        const int i1 = i + FTH, i2 = i + 2 * FTH, i3 = i + 3 * FTH;
        const bool ok1 = i1 < N / 4, ok2 = i2 < N / 4, ok3 = i3 < N / 4;
        f32x4 v0 = f4[i];
        f32x4 v1 = {}, v2 = {}, v3 = {};
        if (ok1) v1 = f4[i1];
        if (ok2) v2 = f4[i2];
        if (ok3) v3 = f4[i3];
        u16x4 w0 = {f2bf(v0.x), f2bf(v0.y), f2bf(v0.z), f2bf(v0.w)};
        *reinterpret_cast<u16x4*>(&row_bf[i * 4]) = w0;
        if (ok1) {
            u16x4 w1 = {f2bf(v1.x), f2bf(v1.y), f2bf(v1.z), f2bf(v1.w)};
            *reinterpret_cast<u16x4*>(&row_bf[i1 * 4]) = w1;
        }
        if (ok2) {
            u16x4 w2 = {f2bf(v2.x), f2bf(v2.y), f2bf(v2.z), f2bf(v2.w)};
            *reinterpret_cast<u16x4*>(&row_bf[i2 * 4]) = w2;
        }
        if (ok3) {
            u16x4 w3 = {f2bf(v3.x), f2bf(v3.y), f2bf(v3.z), f2bf(v3.w)};
            *reinterpret_cast<u16x4*>(&row_bf[i3 * 4]) = w3;
        }
    }
    __syncthreads();

    // Phase 2 (as R12, but each gather exec-predicated on k<cnt): per group one
    // 16B coalesced mt load + 4B cnt + ~cnt LDS gathers + rcp + coalesced NT store.
    const ushort* __restrict__ mtb = mt + (size_t)b * T * PAD;
    const int* __restrict__ cntb = head + b * T;
    float* __restrict__ orow = out + (size_t)(b * C + c) * T;
    for (int t = tid; t < T; t += 2 * FTH) {
        const int t1 = t + FTH;
        const bool ok = t1 < T;
        u16x8 m0 = *reinterpret_cast<const u16x8*>(mtb + (size_t)t * PAD);
        u16x8 m1 = {};
        if (ok) m1 = *reinterpret_cast<const u16x8*>(mtb + (size_t)t1 * PAD);
        const int cn0 = cntb[t];
        const int cn1 = ok ? cntb[t1] : 0;
        float s0 = 0.0f, s1 = 0.0f;
        #pragma unroll
        for (int k = 0; k < PAD; ++k) {
            if (k < cn0) s0 += bf2f(row_bf[m0[k]]);
            if (k < cn1) s1 += bf2f(row_bf[m1[k]]);
        }
        if (cn0 <= PAD)
            __builtin_nontemporal_store(
                s0 * __builtin_amdgcn_rcpf(fmaxf((float)cn0, 1.0f)), orow + t);
        if (ok && cn1 <= PAD)
            __builtin_nontemporal_store(
                s1 * __builtin_amdgcn_rcpf(fmaxf((float)cn1, 1.0f)), orow + t1);
    }

    // Epilogue: heavy groups (count>PAD, ~22 per mesh) — mt + overflow scan
    const int H = hcnt[b];
    if (H > 0) {
        const int O = ocnt[b];
        const unsigned* __restrict__ ofb = of + (size_t)b * N;
        for (int i = tid; i < H; i += FTH) {
            const int g = hg[b * MAXH + i];
            const ushort* mg = mtb + (size_t)g * PAD;
            float s = 0.0f;
            #pragma unroll
            for (int k = 0; k < PAD; ++k) s += bf2f(row_bf[mg[k]]);
            for (int e = 0; e < O; ++e) {
                unsigned w = ofb[e];
                if ((w >> 16) == (unsigned)g) s += bf2f(row_bf[w & 0xFFFFu]);
            }
            orow[g] = s / (float)cntb[g];
        }
    }
}

// ---- fallback (ws too small): R2 LDS-atomic kernel ----
static constexpr int BLK = 1024;
__global__ void __launch_bounds__(256) hemp_zero_kernel(int* __restrict__ counts) {
    int i = blockIdx.x * 256 + threadIdx.x;
    if (i < B * T) counts[i] = 0;
}
__global__ void __launch_bounds__(256) hemp_count1_kernel(const int* __restrict__ gid,
                                                          int* __restrict__ counts) {
    int idx = blockIdx.x * 256 + threadIdx.x;
    if (idx < B * N) {
        int b = idx / N;
        atomicAdd(&counts[b * T + gid[idx]], 1);
    }
}
__global__ void __launch_bounds__(BLK) hemp_atomic_kernel(const float* __restrict__ feat,
                                                          const int* __restrict__ gid,
                                                          const int* __restrict__ counts,
                                                          float* __restrict__ out) {
    extern __shared__ float lds_sum[];
    const int tid = threadIdx.x;
    const int b = blockIdx.x >> 8;
    const int c = blockIdx.x & 255;
    float4* ls4 = reinterpret_cast<float4*>(lds_sum);
    for (int t = tid; t < T / 4; t += BLK) ls4[t] = make_float4(0.f, 0.f, 0.f, 0.f);
    __syncthreads();
    const float4* f4 = reinterpret_cast<const float4*>(feat + (size_t)(b * C + c) * N);
    const int4* g4 = reinterpret_cast<const int4*>(gid + (size_t)b * N);
    for (int i = tid; i < N / 4; i += BLK) {
        float4 v = f4[i];
        int4 g = g4[i];
        unsafeAtomicAdd(&lds_sum[g.x], v.x);
        unsafeAtomicAdd(&lds_sum[g.y], v.y);
        unsafeAtomicAdd(&lds_sum[g.z], v.z);
        unsafeAtomicAdd(&lds_sum[g.w], v.w);
    }
    __syncthreads();
    const int4* cnt4 = reinterpret_cast<const int4*>(counts + (size_t)b * T);
    float4* out4 = reinterpret_cast<float4*>(out + (size_t)(b * C + c) * T);
    for (int t = tid; t < T / 4; t += BLK) {
        int4 cn = cnt4[t];
        float4 s = ls4[t];
        float4 r;
        r.x = s.x / fmaxf((float)cn.x, 1.0f);
        r.y = s.y / fmaxf((float)cn.y, 1.0f);
        r.z = s.z / fmaxf((float)cn.z, 1.0f);
        r.w = s.w / fmaxf((float)cn.w, 1.0f);
        out4[t] = r;
    }
}

extern "C" void kernel_launch(void* const* d_in, const int* in_sizes, int n_in,
                              void* d_out, int out_size, void* d_ws, size_t ws_size,
                              hipStream_t stream) {
    const float* feat = (const float*)d_in[0];
    const int* gid = (const int*)d_in[1];
    float* out = (float*)d_out;

    // ws: head[B*T] i32 | mt[B*T*PAD] u16 | of[B*N] u32 | hg[B*MAXH] i32 | hcnt[B] | ocnt[B]
    char* p = (char*)d_ws;
    int* head = (int*)p;            p += (size_t)B * T * 4;
    ushort* mt = (ushort*)p;        p += (size_t)B * T * PAD * 2;
    unsigned* of = (unsigned*)p;    p += (size_t)B * N * 4;
    int* hg = (int*)p;              p += (size_t)B * MAXH * 4;
    int* hcnt = (int*)p;            p += (size_t)B * 4;
    int* ocnt = (int*)p;            p += (size_t)B * 4;
    size_t need = (size_t)(p - (char*)d_ws);

    if (ws_size >= need) {
        hemp_init_kernel<<<640, 256, 0, stream>>>(head, hcnt, ocnt);
        hemp_fill_kernel<<<(B * N / 4 + 255) / 256, 256, 0, stream>>>(gid, head, mt, of,
                                                                      hg, hcnt, ocnt);
        hemp_fused_kernel<<<B * C, FTH, 0, stream>>>(feat, mt, head, of, hg,
                                                     hcnt, ocnt, out);
    } else {
        int* cnts = (int*)d_ws;
        hemp_zero_kernel<<<(B * T + 255) / 256, 256, 0, stream>>>(cnts);
        hemp_count1_kernel<<<(B * N + 255) / 256, 256, 0, stream>>>(gid, cnts);
        const size_t lds_bytes = (size_t)T * sizeof(float);
        hipFuncSetAttribute(reinterpret_cast<const void*>(hemp_atomic_kernel),
                            hipFuncAttributeMaxDynamicSharedMemorySize, (int)lds_bytes);
        hemp_atomic_kernel<<<B * C, BLK, lds_bytes, stream>>>(feat, gid, cnts, out);
    }
}

// Round 15
// 142.622 us; speedup vs baseline: 1.7258x; 1.0209x over previous
//
#include <hip/hip_runtime.h>

// HalfEdgeMeshPool: segment-mean over groups.
// feat: [B, C, N] f32, gid: [B, N] i32 in [0,T), out: [B, C, T] f32.
//
// R1/R2: LDS f32 atomics serialize ~3.2 cyc/lane -> 428us floor.
// R3: random 4B global gather = 14.5x line over-fetch -> 1.7ms.
// R5/R6: sort+transpose (820MB, 2 passes) -> 250us.
// R7: fused single-pass, 160KB LDS -> 318us (1 block/CU, serialized phases).
// R8: fused, 80KB LDS, mt[t][8] + sentinel -> 199us. R11: 1024-thr -> 142us.
// R12: prepass trim + rcp -> 140us. R13: slot-major -> 246us REGRESSION.
// R14: predicated gathers -> 146us null: sentinel broadcast already made empty
//      slots free; removing sentinel added garbage-address conflicts.
// R15: R12 + cnt derived from sentinel-popcount (deletes the dependent 4B cnt
//      load + 80KB/block L2 traffic; heavy groups = full-table, registered at
//      8th member, epilogue reads true cnt) + software-pipelined mt loads.
static constexpr int B = 8;
static constexpr int C = 256;
static constexpr int N = 40000;
static constexpr int T = 20000;
static constexpr int PAD = 8;                  // mt slots per group
static constexpr int MAXH = N / PAD + 8;       // heavy-group cap per b (cnt>=8)
static constexpr int LDSU = 40448;             // row_bf u16 slots (data + zero pad)
static constexpr int FTH = 1024;               // fused block threads
static constexpr ushort SENT = 40000;          // sentinel -> zeroed LDS slot

typedef float  f32x4 __attribute__((ext_vector_type(4)));
typedef ushort u16x4 __attribute__((ext_vector_type(4)));
typedef ushort u16x8 __attribute__((ext_vector_type(8)));

__device__ __forceinline__ ushort f2bf(float v) {
    unsigned u = __float_as_uint(v);
    u += 0x7FFFu + ((u >> 16) & 1u);  // round-to-nearest-even
    return (ushort)(u >> 16);
}
__device__ __forceinline__ float bf2f(ushort u) {
    return __uint_as_float((unsigned)u << 16);
}

// ---- init: head=0, mt=sentinel, hcnt=ocnt=0 ----
__global__ void __launch_bounds__(256) hemp_init_kernel(int* __restrict__ head,
                                                        unsigned* __restrict__ mt32,
                                                        int* __restrict__ hcnt,
                                                        int* __restrict__ ocnt) {
    const int stride = gridDim.x * 256;
    int i = blockIdx.x * 256 + threadIdx.x;
    for (int k = i; k < B * T * PAD / 2; k += stride) mt32[k] = 0x9C409C40u;
    for (int k = i; k < B * T; k += stride) head[k] = 0;
    if (i < B) { hcnt[i] = 0; ocnt[i] = 0; }
}

// ---- fill (int4): rank r -> mt slot; r==PAD-1 registers heavy (cnt>=8);
//      r>=PAD -> overflow list ----
__global__ void __launch_bounds__(256) hemp_fill_kernel(const int* __restrict__ gid,
                                                        int* __restrict__ head,
                                                        ushort* __restrict__ mt,
                                                        unsigned* __restrict__ of,
                                                        int* __restrict__ hg,
                                                        int* __restrict__ hcnt,
                                                        int* __restrict__ ocnt) {
    int idx = blockIdx.x * 256 + threadIdx.x;
    if (idx >= B * N / 4) return;
    const int b = idx / (N / 4);
    const int i4 = idx - b * (N / 4);
    const int4 g = reinterpret_cast<const int4*>(gid + (size_t)b * N)[i4];
    int* hb = head + b * T;
    const int n = i4 * 4;
    #pragma unroll
    for (int k = 0; k < 4; ++k) {
        const int gg = (k == 0) ? g.x : (k == 1) ? g.y : (k == 2) ? g.z : g.w;
        const int r = atomicAdd(&hb[gg], 1);  // head ends as per-group count
        if (r < PAD) {
            mt[((size_t)(b * T + gg)) * PAD + r] = (ushort)(n + k);
            if (r == PAD - 1) {  // 8th member: group leaves the fast path
                int h = atomicAdd(&hcnt[b], 1);
                hg[b * MAXH + h] = gg;
            }
        } else {
            int o = atomicAdd(&ocnt[b], 1);
            of[(size_t)b * N + o] = ((unsigned)gg << 16) | (unsigned)(n + k);
        }
    }
}

__device__ __forceinline__ void proc_group(const u16x8 m, const ushort* row_bf,
                                           float& s, int& cnt) {
    s = 0.0f;
    cnt = 0;
    #pragma unroll
    for (int k = 0; k < PAD; ++k) {
        s += bf2f(row_bf[m[k]]);     // sentinel -> broadcast read of zero slot
        cnt += (m[k] != SENT) ? 1 : 0;
    }
}

// ---- fused: one block per (b,c). Stream row->LDS bf16; pipelined mt loads ----
__global__ void __launch_bounds__(FTH) hemp_fused_kernel(const float* __restrict__ feat,
                                                         const ushort* __restrict__ mt,
                                                         const int* __restrict__ head,
                                                         const unsigned* __restrict__ of,
                                                         const int* __restrict__ hg,
                                                         const int* __restrict__ hcnt,
                                                         const int* __restrict__ ocnt,
                                                         float* __restrict__ out) {
    extern __shared__ ushort row_bf[];  // LDSU u16 = 80896 B -> 2 blocks/CU
    const int tid = threadIdx.x;
    const int b = blockIdx.x >> 8;  // same-b blocks adjacent -> mt L2-hot
    const int c = blockIdx.x & 255;

    // zero the pad region (sentinel 40000 lands here)
    if (tid < (LDSU - N) / 4)
        *reinterpret_cast<u16x4*>(&row_bf[N + tid * 4]) = (u16x4){0, 0, 0, 0};

    // Phase 1: stream feature row into LDS as bf16 (unroll-2 for load depth)
    const f32x4* __restrict__ f4 =
        reinterpret_cast<const f32x4*>(feat + (size_t)(b * C + c) * N);
    for (int i = tid; i < N / 4; i += 2 * FTH) {
        f32x4 v0 = f4[i];
        const int i2 = i + FTH;
        const bool ok = i2 < N / 4;
        f32x4 v1 = {};
        if (ok) v1 = f4[i2];
        u16x4 w0 = {f2bf(v0.x), f2bf(v0.y), f2bf(v0.z), f2bf(v0.w)};
        *reinterpret_cast<u16x4*>(&row_bf[i * 4]) = w0;
        if (ok) {
            u16x4 w1 = {f2bf(v1.x), f2bf(v1.y), f2bf(v1.z), f2bf(v1.w)};
            *reinterpret_cast<u16x4*>(&row_bf[i2 * 4]) = w1;
        }
    }
    __syncthreads();

    // Phase 2: per group: one pipelined 16B mt load -> 8 gathers (empties are
    // same-address broadcasts) -> cnt via popcount -> rcp -> coalesced NT store.
    const ushort* __restrict__ mtb = mt + (size_t)b * T * PAD;
    float* __restrict__ orow = out + (size_t)(b * C + c) * T;
    u16x8 m0 = {}, m1 = {};
    {
        if (tid < T) m0 = *reinterpret_cast<const u16x8*>(mtb + (size_t)tid * PAD);
        if (tid + FTH < T)
            m1 = *reinterpret_cast<const u16x8*>(mtb + (size_t)(tid + FTH) * PAD);
    }
    for (int t = tid; t < T; t += 2 * FTH) {
        const int t1 = t + FTH;
        const int tn = t + 2 * FTH, tn1 = tn + FTH;
        u16x8 n0 = {}, n1 = {};
        if (tn < T) n0 = *reinterpret_cast<const u16x8*>(mtb + (size_t)tn * PAD);
        if (tn1 < T) n1 = *reinterpret_cast<const u16x8*>(mtb + (size_t)tn1 * PAD);
        float s0, s1;
        int cn0, cn1;
        proc_group(m0, row_bf, s0, cn0);
        proc_group(m1, row_bf, s1, cn1);
        if (cn0 < PAD)
            __builtin_nontemporal_store(
                s0 * __builtin_amdgcn_rcpf(fmaxf((float)cn0, 1.0f)), orow + t);
        if (t1 < T && cn1 < PAD)
            __builtin_nontemporal_store(
                s1 * __builtin_amdgcn_rcpf(fmaxf((float)cn1, 1.0f)), orow + t1);
        m0 = n0;
        m1 = n1;
    }

    // Epilogue: heavy groups (cnt>=8, ~45/mesh): 8 table members + of-scan
    const int H = hcnt[b];
    if (H > 0) {
        const int O = ocnt[b];
        const int* __restrict__ cntb = head + b * T;
        const unsigned* __restrict__ ofb = of + (size_t)b * N;
        for (int i = tid; i < H; i += FTH) {
            const int g = hg[b * MAXH + i];
            const ushort* mg = mtb + (size_t)g * PAD;
            float s = 0.0f;
            #pragma unroll
            for (int k = 0; k < PAD; ++k) s += bf2f(row_bf[mg[k]]);
            for (int e = 0; e < O; ++e) {
                unsigned w = ofb[e];
                if ((w >> 16) == (unsigned)g) s += bf2f(row_bf[w & 0xFFFFu]);
            }
            orow[g] = s / (float)cntb[g];
        }
    }
}

// ---- fallback (ws too small): R2 LDS-atomic kernel ----
static constexpr int BLK = 1024;
__global__ void __launch_bounds__(256) hemp_zero_kernel(int* __restrict__ counts) {
    int i = blockIdx.x * 256 + threadIdx.x;
    if (i < B * T) counts[i] = 0;
}
__global__ void __launch_bounds__(256) hemp_count1_kernel(const int* __restrict__ gid,
                                                          int* __restrict__ counts) {
    int idx = blockIdx.x * 256 + threadIdx.x;
    if (idx < B * N) {
        int b = idx / N;
        atomicAdd(&counts[b * T + gid[idx]], 1);
    }
}
__global__ void __launch_bounds__(BLK) hemp_atomic_kernel(const float* __restrict__ feat,
                                                          const int* __restrict__ gid,
                                                          const int* __restrict__ counts,
                                                          float* __restrict__ out) {
    extern __shared__ float lds_sum[];
    const int tid = threadIdx.x;
    const int b = blockIdx.x >> 8;
    const int c = blockIdx.x & 255;
    float4* ls4 = reinterpret_cast<float4*>(lds_sum);
    for (int t = tid; t < T / 4; t += BLK) ls4[t] = make_float4(0.f, 0.f, 0.f, 0.f);
    __syncthreads();
    const float4* f4 = reinterpret_cast<const float4*>(feat + (size_t)(b * C + c) * N);
    const int4* g4 = reinterpret_cast<const int4*>(gid + (size_t)b * N);
    for (int i = tid; i < N / 4; i += BLK) {
        float4 v = f4[i];
        int4 g = g4[i];
        unsafeAtomicAdd(&lds_sum[g.x], v.x);
        unsafeAtomicAdd(&lds_sum[g.y], v.y);
        unsafeAtomicAdd(&lds_sum[g.z], v.z);
        unsafeAtomicAdd(&lds_sum[g.w], v.w);
    }
    __syncthreads();
    const int4* cnt4 = reinterpret_cast<const int4*>(counts + (size_t)b * T);
    float4* out4 = reinterpret_cast<float4*>(out + (size_t)(b * C + c) * T);
    for (int t = tid; t < T / 4; t += BLK) {
        int4 cn = cnt4[t];
        float4 s = ls4[t];
        float4 r;
        r.x = s.x / fmaxf((float)cn.x, 1.0f);
        r.y = s.y / fmaxf((float)cn.y, 1.0f);
        r.z = s.z / fmaxf((float)cn.z, 1.0f);
        r.w = s.w / fmaxf((float)cn.w, 1.0f);
        out4[t] = r;
    }
}

extern "C" void kernel_launch(void* const* d_in, const int* in_sizes, int n_in,
                              void* d_out, int out_size, void* d_ws, size_t ws_size,
                              hipStream_t stream) {
    const float* feat = (const float*)d_in[0];
    const int* gid = (const int*)d_in[1];
    float* out = (float*)d_out;

    // ws: head[B*T] i32 | mt[B*T*PAD] u16 | of[B*N] u32 | hg[B*MAXH] i32 | hcnt[B] | ocnt[B]
    char* p = (char*)d_ws;
    int* head = (int*)p;            p += (size_t)B * T * 4;
    ushort* mt = (ushort*)p;        p += (size_t)B * T * PAD * 2;
    unsigned* of = (unsigned*)p;    p += (size_t)B * N * 4;
    int* hg = (int*)p;              p += (size_t)B * MAXH * 4;
    int* hcnt = (int*)p;            p += (size_t)B * 4;
    int* ocnt = (int*)p;            p += (size_t)B * 4;
    size_t need = (size_t)(p - (char*)d_ws);

    if (ws_size >= need) {
        hemp_init_kernel<<<2560, 256, 0, stream>>>(head, (unsigned*)mt, hcnt, ocnt);
        hemp_fill_kernel<<<(B * N / 4 + 255) / 256, 256, 0, stream>>>(gid, head, mt, of,
                                                                      hg, hcnt, ocnt);
        const int lds_bytes = LDSU * 2;  // 80896 B -> 2 blocks/CU
        hipFuncSetAttribute(reinterpret_cast<const void*>(hemp_fused_kernel),
                            hipFuncAttributeMaxDynamicSharedMemorySize, lds_bytes);
        hemp_fused_kernel<<<B * C, FTH, lds_bytes, stream>>>(feat, mt, head, of, hg,
                                                             hcnt, ocnt, out);
    } else {
        int* cnts = (int*)d_ws;
        hemp_zero_kernel<<<(B * T + 255) / 256, 256, 0, stream>>>(cnts);
        hemp_count1_kernel<<<(B * N + 255) / 256, 256, 0, stream>>>(gid, cnts);
        const size_t lds_bytes = (size_t)T * sizeof(float);
        hipFuncSetAttribute(reinterpret_cast<const void*>(hemp_atomic_kernel),
                            hipFuncAttributeMaxDynamicSharedMemorySize, (int)lds_bytes);
        hemp_atomic_kernel<<<B * C, BLK, lds_bytes, stream>>>(feat, gid, cnts, out);
    }
}